// Round 10
// baseline (161.446 us; speedup 1.0000x reference)
//
#include <hip/hip_runtime.h>
#include <cmath>

#define NT 2048
#define NX 128
#define NXF 512
#define NF 4097
#define NFP 4104     // padded row length (complex) for f-axis rows
#define TDP 2056     // padded row length for t-axis rows
#define NBATCH 4
#define EPSF 1.1920929e-07f
#define SOUND_C 1540.0f

// LDS skew addressing: addr = e + 2*(e>>4). Bijective; <=2-way bank conflicts
// for every access pattern used here. 2-way is free on CDNA4.
__device__ __forceinline__ int SK(int e) { return e + 2 * (e >> 4); }

struct FKP {
  float ds, inv_ds, inv_kx_den, v_erm, kz_coef, ph_rev, dx_coef;
};

__device__ __forceinline__ float2 cmul(float2 a, float2 b) {
  return make_float2(a.x * b.x - a.y * b.y, a.x * b.y + a.y * b.x);
}
// e^{2*pi*i*u}, any u. v_cos/v_sin take REVOLUTIONS natively; fract reduces.
__device__ __forceinline__ float2 twid(float u) {
  const float f = u - floorf(u);
  return make_float2(__builtin_amdgcn_cosf(f), __builtin_amdgcn_sinf(f));
}
__device__ __forceinline__ float2 twidf(float u) { return twid(u); }
// Constant twiddle e^{sgn*2pi*i*k/16}, k in [0,4) compile-time -> literals.
__device__ __forceinline__ float2 twc16(int k, float sgn) {
  const float C[4]  = {1.0f, 0.923879532511f, 0.707106781187f, 0.382683432365f};
  const float Sn[4] = {0.0f, 0.382683432365f, 0.707106781187f, 0.923879532511f};
  return make_float2(C[k], sgn * Sn[k]);
}
// base-4 digit reversals
__device__ __forceinline__ int dr4_3(unsigned m) {
  unsigned r = __brev(m) >> 26;
  return (int)(((r & 0x15u) << 1) | ((r >> 1) & 0x15u));
}
__device__ __forceinline__ int dr4_4(unsigned m) {
  unsigned r = __brev(m) >> 24;
  return (int)(((r & 0x55u) << 1) | ((r >> 1) & 0x55u));
}
__device__ __forceinline__ int dr4_5(unsigned m) {
  unsigned r = __brev(m) >> 22;
  return (int)(((r & 0x155u) << 1) | ((r >> 1) & 0x155u));
}

// 4-pt DFT, no twiddle. sgn=-1 fwd, +1 inv.
__device__ __forceinline__ void dft4(float2& A, float2& B, float2& C, float2& D, float sgn) {
  float2 t0 = make_float2(A.x + C.x, A.y + C.y);
  float2 t1 = make_float2(A.x - C.x, A.y - C.y);
  float2 t2 = make_float2(B.x + D.x, B.y + D.y);
  float2 t3 = make_float2(B.x - D.x, B.y - D.y);
  float2 r  = make_float2(-sgn * t3.y, sgn * t3.x);
  A = make_float2(t0.x + t2.x, t0.y + t2.y);
  B = make_float2(t1.x + r.x, t1.y + r.y);
  C = make_float2(t0.x - t2.x, t0.y - t2.y);
  D = make_float2(t1.x - r.x, t1.y - r.y);
}
// DIT radix-4 butterfly with precomputed twiddles (pre-multiply then DFT4).
__device__ __forceinline__ void bfly4r(float2& A, float2& B, float2& C, float2& D,
                                       float2 w1, float2 w2, float2 w3, float sgn) {
  B = cmul(B, w1); C = cmul(C, w2); D = cmul(D, w3);
  dft4(A, B, C, D, sgn);
}
__device__ __forceinline__ void twtrip(float u, float2& w1, float2& w2, float2& w3) {
  w1 = twid(u); w2 = cmul(w1, w1); w3 = cmul(w2, w1);
}

// Merged radix-16 phase (two DIT radix-4 levels mh=S and mh=4S in registers).
// Level-2 twiddles derived from ONE base twiddle x constant rotations.
template<int S>
__device__ __forceinline__ void mstage(float2* __restrict__ s, int base, int kb, float sgn) {
  float2 w[16];
#pragma unroll
  for (int m = 0; m < 16; ++m) w[m] = s[SK(base + S * m)];
  {
    float2 a1, a2, a3; twtrip(sgn * (float)kb * (1.0f / (4 * S)), a1, a2, a3);
#pragma unroll
    for (int a = 0; a < 4; ++a)
      bfly4r(w[4 * a], w[4 * a + 1], w[4 * a + 2], w[4 * a + 3], a1, a2, a3, sgn);
  }
  {
    const float2 wb = twid(sgn * (float)kb * (1.0f / (16 * S)));
#pragma unroll
    for (int c = 0; c < 4; ++c) {
      float2 b1 = cmul(wb, twc16(c, sgn));
      float2 b2 = cmul(b1, b1);
      float2 b3 = cmul(b2, b1);
      bfly4r(w[c], w[4 + c], w[8 + c], w[12 + c], b1, b2, b3, sgn);
    }
  }
#pragma unroll
  for (int m = 0; m < 16; ++m) s[SK(base + S * m)] = w[m];
}

// K0: transpose input (nt,nx) -> DT (nx, TDP); also init per-slot max-key.
__global__ void __launch_bounds__(256) k_tr(const float* __restrict__ data,
                                            float* __restrict__ dt,
                                            float* __restrict__ red,
                                            size_t slot4, int b_base) {
  __shared__ float tile[32][33];
  if (threadIdx.x == 0 && blockIdx.x == 0 && blockIdx.y == 0)
    *(unsigned*)&red[blockIdx.z * slot4] = 0u;
  const int tx = threadIdx.x & 31;
  const int ty = threadIdx.x >> 5;
  const int t0 = blockIdx.x * 32;
  const int x0 = blockIdx.y * 32;
  const float* In = data + (size_t)(b_base + blockIdx.z) * NT * NX;
  float* Dt = dt + blockIdx.z * slot4;
  for (int i = ty; i < 32; i += 8)
    tile[i][tx] = In[(size_t)(t0 + i) * NX + x0 + tx];
  __syncthreads();
  for (int i = ty; i < 32; i += 8)
    Dt[(size_t)(x0 + i) * TDP + t0 + tx] = tile[tx][i];
}

// K1: per x, 8192-pt R2C FFT (4096 complex, 3 merged radix-16 phases) + phase.
__global__ void __launch_bounds__(256) k_fft_t(const float* __restrict__ dt,
                                               float2* __restrict__ o1t,
                                               size_t slot4, size_t slot8, FKP P) {
  __shared__ float2 nat[1152];
  __shared__ float2 s[4608];
  const int x = blockIdx.x, tid = threadIdx.x;
  const float2* row2 = (const float2*)(dt + blockIdx.z * slot4 + (size_t)x * TDP);
  float2* O1 = o1t + blockIdx.z * slot8 + (size_t)x * NFP;
  for (int m = tid; m < 1024; m += 256) nat[SK(m)] = row2[m];
  __syncthreads();
  // M1: merged stages (1,4); input zero-structure -> broadcast + level-2 bfly.
  {
    const int m0 = dr4_4((unsigned)tid);
    const float2 v0 = nat[SK(m0)];
    const float2 v1 = nat[SK(m0 + 256)];
    const float2 v2 = nat[SK(m0 + 512)];
    const float2 v3 = nat[SK(m0 + 768)];
    const int base = tid << 4;
#pragma unroll
    for (int k = 0; k < 4; ++k) {
      float2 A = v0, B = v1, C = v2, D = v3;
      if (k == 0) {
        dft4(A, B, C, D, -1.0f);
      } else {
        float2 w1 = twc16(k, -1.0f);
        float2 w2 = cmul(w1, w1);
        float2 w3 = cmul(w2, w1);
        bfly4r(A, B, C, D, w1, w2, w3, -1.0f);
      }
      s[SK(base + k)] = A; s[SK(base + 4 + k)] = B;
      s[SK(base + 8 + k)] = C; s[SK(base + 12 + k)] = D;
    }
  }
  __syncthreads();
  mstage<16>(s, ((tid >> 4) << 8) | (tid & 15), tid & 15, -1.0f);
  __syncthreads();
  mstage<256>(s, tid, tid, -1.0f);
  __syncthreads();
  // R2C unpack + t_delay phase
  for (int k = tid; k < NF; k += 256) {
    const int ka = k & 4095, kb = (4096 - k) & 4095;
    const float2 Ck = s[SK(ka)];
    const float2 Cm = s[SK(kb)];
    float2 E = make_float2(0.5f * (Ck.x + Cm.x), 0.5f * (Ck.y - Cm.y));
    float2 T = make_float2(0.5f * (Ck.x - Cm.x), 0.5f * (Ck.y + Cm.y));
    float2 WT = cmul(twid((float)k * (-1.0f / 8192.0f)), T);
    float2 X = make_float2(E.x + WT.y, E.y - WT.x);   // E - i*(W*T)
    float2 ph = twidf(P.ph_rev * (float)(x * k));
    O1[k] = cmul(X, ph);
  }
}

// K2: per 8 f-rows, 512-pt FFT along x (2 halves x 4^4), register-merged:
// coalesced gather load -> M1 (mh=1 broadcast + mh=4) in regs -> mstage<16>
// (mh=16,64) -> store with fused cross radix-2 + evanescent mask, transposed
// write OT[j][i]. 2 barriers, ~half the LDS traffic of the staged version.
#define R2P 580
__global__ void __launch_bounds__(256) k_fft_x(const float2* __restrict__ o1t,
                                               float2* __restrict__ ot,
                                               size_t slot8, FKP P) {
  __shared__ float2 s[8 * R2P];
  const int i0 = blockIdx.x * 8;
  const int tid = threadIdx.x;
  const float2* O1 = o1t + blockIdx.z * slot8;
  float2* OT = ot + blockIdx.z * slot8;
  // unit: row = tid&7 (f-row), hu = tid>>3: half b = hu&1 (x parity), u = hu>>1
  const int row = tid & 7, hu = tid >> 3;
  const int b = hu & 1, u = hu >> 1;
  const int i = i0 + row;
  {
    float2 v[4];
#pragma unroll
    for (int c = 0; c < 4; ++c) {
      const int m = dr4_3((unsigned)(4 * u + c));
      const int xx = 2 * m + b;
      v[c] = (i < NF) ? O1[(size_t)xx * NFP + i] : make_float2(0.f, 0.f);
    }
    float2* r = s + row * R2P;
    const int base = (b << 8) + (u << 4);
#pragma unroll
    for (int k = 0; k < 4; ++k) {
      float2 A = v[0], B = v[1], C = v[2], D = v[3];
      if (k == 0) {
        dft4(A, B, C, D, -1.0f);
      } else {
        float2 w1 = twc16(k, -1.0f);
        float2 w2 = cmul(w1, w1);
        float2 w3 = cmul(w2, w1);
        bfly4r(A, B, C, D, w1, w2, w3, -1.0f);
      }
      r[SK(base + k)] = A; r[SK(base + 4 + k)] = B;
      r[SK(base + 8 + k)] = C; r[SK(base + 12 + k)] = D;
    }
  }
  __syncthreads();
  // levels mh=16,64 of each 256-half
  mstage<16>(s + row * R2P, (b << 8) + u, u, -1.0f);
  __syncthreads();
  // store: fused radix-2 cross-half combine + mask, transposed write
  for (int idx = tid; idx < 512 * 8; idx += 256) {
    const int j = idx >> 3, ii = idx & 7;
    const int io = i0 + ii;
    if (io >= NF) continue;
    const int k = j & 255;
    const float2* r = s + ii * R2P;
    const float2 E = r[SK(k)];
    const float2 O = r[SK(256 + k)];
    const float2 WO = cmul(twid((float)k * (-1.0f / 512.0f)), O);
    float2 vv = (j < 256) ? make_float2(E.x + WO.x, E.y + WO.y)
                          : make_float2(E.x - WO.x, E.y - WO.y);
    const float f = P.ds * (float)io;
    const int kn = (j <= 256) ? j : j - 512;
    const float kx = fabsf((float)kn * P.inv_kx_den);
    if (f / (kx + EPSF) < SOUND_C) vv = make_float2(0.f, 0.f);
    OT[(size_t)j * NFP + io] = vv;
  }
}

// K4: per kx-column j in [0,256]: Stolt gather at digit-reversed positions
// fused with merged stages (1,4); then 2 merged radix-16 phases and the cross
// radix-2; dx-phase; writes TDT[j][t], t<NT. Unscaled.
__global__ void __launch_bounds__(512) k_ifft_t(const float2* __restrict__ ot,
                                                float2* __restrict__ tdt,
                                                size_t slot8, FKP P) {
  __shared__ float2 s[9216];
  const int j = blockIdx.x;                  // 0..256
  const int jm = (NXF - j) & (NXF - 1);
  const int t = threadIdx.x;
  const float2* OT = ot + blockIdx.z * slot8;
  float2* T = tdt + blockIdx.z * slot8 + (size_t)j * TDP;
  const float kxj = (float)j * P.inv_kx_den;
  const float kx2 = kxj * kxj;
  const float2* rowj = OT + (size_t)j * NFP;
  const float2* rowm = OT + (size_t)jm * NFP;
  // M1: thread owns digit-rev positions 16t..16t+15. Position 16t+m holds
  // spectrum sample n = 2*(1024*(m&3) + 256*(m>>2) + dr4_4(t&255)) + (t>>8).
  {
    const int tau = t & 255, half = t >> 8;
    const int m0 = dr4_4((unsigned)tau);
    float2 w[16];
#pragma unroll
    for (int m = 0; m < 16; ++m) {
      const int ci = (m & 3) * 1024 + (m >> 2) * 256 + m0;
      const int n = 2 * ci + half;
      const bool mir = (n > 4096);
      const int r = mir ? (8192 - n) : n;
      const float2* rw = mir ? rowm : rowj;
      float2 v = make_float2(0.f, 0.f);
      if (r > 0) {
        const float f = P.ds * (float)r;
        const float kz = f * P.kz_coef;
        const float fkz = P.v_erm * sqrtf(kx2 + kz * kz);
        const float iq = fkz * P.inv_ds;
        if (iq < 4095.0f) {
          const float flf = floorf(iq);
          const int fl = (int)flf;
          const float lw = iq - flf;
          const float2 v0 = rw[fl], v1 = rw[fl + 1];
          const float sc = f / (fkz + EPSF);
          v.x = (v0.x + (v1.x - v0.x) * lw) * sc;
          v.y = (v0.y + (v1.y - v0.y) * lw) * (mir ? -sc : sc);
        }
      }
      w[m] = v;
    }
#pragma unroll
    for (int a = 0; a < 4; ++a) dft4(w[4 * a], w[4 * a + 1], w[4 * a + 2], w[4 * a + 3], 1.0f);
    dft4(w[0], w[4], w[8], w[12], 1.0f);
#pragma unroll
    for (int k = 1; k < 4; ++k) {
      float2 w1 = twc16(k, 1.0f);
      float2 w2 = cmul(w1, w1);
      float2 w3 = cmul(w2, w1);
      bfly4r(w[k], w[4 + k], w[8 + k], w[12 + k], w1, w2, w3, 1.0f);
    }
    const int base = t << 4;
#pragma unroll
    for (int m = 0; m < 16; ++m) s[SK(base + m)] = w[m];
  }
  __syncthreads();
  mstage<16>(s, ((t >> 4) << 8) | (t & 15), t & 15, 1.0f);
  __syncthreads();
  mstage<256>(s, ((t >> 8) << 12) | (t & 255), t & 255, 1.0f);
  __syncthreads();
  // cross radix-2 (only outputs t<2048 needed) + dx-phase
  const float dxr = -kxj * P.dx_coef;
#pragma unroll
  for (int i = 0; i < 4; ++i) {
    const int k = t + 512 * i;
    const float2 E = s[SK(k)];
    const float2 O = s[SK(4096 + k)];
    const float2 WO = cmul(twid((float)k * (1.0f / 8192.0f)), O);
    const float2 y = make_float2(E.x + WO.x, E.y + WO.y);
    T[k] = cmul(y, twidf(dxr * (float)k));
  }
}

// K5: per 8 t-rows: Hermitian C2R 512-pt inverse x-FFT via 256-pt complex
// IFFT; writes real MIGT[x][t]. Unscaled. DC/Nyquist Im projected out.
#define SXA 260
#define SXC 292
__global__ void __launch_bounds__(256) k_c2r_x(const float2* __restrict__ tdt,
                                               float* __restrict__ migt,
                                               size_t slot8, size_t slot4) {
  __shared__ float2 sx[8 * SXA];
  __shared__ float2 sc[8 * SXC];
  const int t0 = blockIdx.x * 8;
  const int tid = threadIdx.x;
  const float2* T = tdt + blockIdx.z * slot8;
  float* M = migt + blockIdx.z * slot4;
  for (int idx = tid; idx < 257 * 8; idx += 256) {
    const int tt = idx & 7, jj = idx >> 3;
    float2 v = T[(size_t)jj * TDP + t0 + tt];
    if (jj == 0 || jj == 256) v.y = 0.0f;
    sx[tt * SXA + jj] = v;
  }
  __syncthreads();
  for (int idx = tid; idx < 129 * 8; idx += 256) {
    const int row = idx & 7, k = idx >> 3;
    const float2* X = sx + row * SXA;
    float2* Cb = sc + row * SXC;
    const float2 Xk = X[k];
    const float2 Xm = X[256 - k];
    float2 Ef = make_float2(0.5f * (Xk.x + Xm.x), 0.5f * (Xk.y - Xm.y));
    float2 Tm = make_float2(0.5f * (Xk.x - Xm.x), 0.5f * (Xk.y + Xm.y));
    float2 Of = cmul(twid((float)k * (1.0f / 512.0f)), Tm);
    Cb[SK(dr4_4((unsigned)k))] = make_float2(Ef.x - Of.y, Ef.y + Of.x);
    if (k > 0 && k < 128)
      Cb[SK(dr4_4((unsigned)(256 - k)))] = make_float2(Ef.x + Of.y, Of.x - Ef.y);
  }
  __syncthreads();
  for (int mh = 1; mh <= 64; mh *= 4) {
    const float inv = 1.0f / (float)(4 * mh);
    for (int t = tid; t < 8 * 64; t += 256) {
      const int row = t >> 6, q = t & 63;
      const int k = q & (mh - 1);
      const int i0 = ((q & ~(mh - 1)) << 2) + k;
      float2* r = sc + row * SXC;
      float2 A = r[SK(i0)], B = r[SK(i0 + mh)], C = r[SK(i0 + 2 * mh)], D = r[SK(i0 + 3 * mh)];
      if (mh > 1) {
        float2 w1, w2, w3; twtrip((float)k * inv, w1, w2, w3);
        bfly4r(A, B, C, D, w1, w2, w3, 1.0f);
      } else {
        dft4(A, B, C, D, 1.0f);
      }
      r[SK(i0)] = A; r[SK(i0 + mh)] = B; r[SK(i0 + 2 * mh)] = C; r[SK(i0 + 3 * mh)] = D;
    }
    __syncthreads();
  }
  for (int idx = tid; idx < 128 * 8; idx += 256) {
    const int x = idx >> 3, tt = idx & 7;
    const float2 c = sc[tt * SXC + SK(x >> 1)];
    M[(size_t)x * TDP + t0 + tt] = (x & 1) ? c.y : c.x;
  }
}

// K6: per x-column Hilbert (2048 = 2*4^5 mixed DIF -> mask(digit-rev) -> DIT)
// + dB via 10*log10(mag^2); block max -> monotone-uint atomicMax.
__global__ void __launch_bounds__(512) k_hilbert(const float* __restrict__ migt,
                                                 float* __restrict__ migdb,
                                                 float* __restrict__ red,
                                                 size_t slot4) {
  __shared__ float2 s[2304];
  __shared__ float rmax[512];
  const int x = blockIdx.x, tid = threadIdx.x;
  const float* Mr = migt + blockIdx.z * slot4 + (size_t)x * TDP;
  float* Db = migdb + blockIdx.z * slot4 + (size_t)x * TDP;
#pragma unroll
  for (int i = 0; i < 4; ++i) {
    const int p = tid + 512 * i;
    s[SK(p)] = make_float2(Mr[p], 0.0f);
  }
  __syncthreads();
  // forward: radix-2 DIF (stride 1024), post-twiddle W^-p
#pragma unroll
  for (int i = 0; i < 2; ++i) {
    const int p = tid + 512 * i;
    const float2 a = s[SK(p)], b = s[SK(p + 1024)];
    s[SK(p)] = make_float2(a.x + b.x, a.y + b.y);
    s[SK(p + 1024)] = cmul(make_float2(a.x - b.x, a.y - b.y),
                           twid(-(float)p * (1.0f / 2048.0f)));
  }
  __syncthreads();
  // per-half radix-4 DIF stages
  for (int mh = 256; mh >= 1; mh >>= 2) {
    const int half = tid >> 8, q = tid & 255;
    const int k = q & (mh - 1);
    const int i0 = (half << 10) + ((q & ~(mh - 1)) << 2) + k;
    float2 A = s[SK(i0)], B = s[SK(i0 + mh)], C = s[SK(i0 + 2 * mh)], D = s[SK(i0 + 3 * mh)];
    dft4(A, B, C, D, -1.0f);
    if (mh > 1) {
      float2 w1, w2, w3; twtrip(-(float)k / (float)(4 * mh), w1, w2, w3);
      B = cmul(B, w1); C = cmul(C, w2); D = cmul(D, w3);
    }
    s[SK(i0)] = A; s[SK(i0 + mh)] = B; s[SK(i0 + 2 * mh)] = C; s[SK(i0 + 3 * mh)] = D;
    __syncthreads();
  }
  // h-mask; position p holds freq k = 2*dr4_5(p&1023) + (p>>10)
#pragma unroll
  for (int i = 0; i < 4; ++i) {
    const int p = tid + 512 * i;
    const int kk = 2 * dr4_5((unsigned)(p & 1023)) + (p >> 10);
    const float hv = (kk == 0 || kk == 1024) ? 1.0f : ((kk < 1024) ? 2.0f : 0.0f);
    float2 v = s[SK(p)];
    s[SK(p)] = make_float2(v.x * hv, v.y * hv);
  }
  __syncthreads();
  // inverse: per-half radix-4 DIT stages
  for (int mh = 1; mh <= 256; mh <<= 2) {
    const int half = tid >> 8, q = tid & 255;
    const int k = q & (mh - 1);
    const int i0 = (half << 10) + ((q & ~(mh - 1)) << 2) + k;
    float2 A = s[SK(i0)], B = s[SK(i0 + mh)], C = s[SK(i0 + 2 * mh)], D = s[SK(i0 + 3 * mh)];
    if (mh > 1) {
      float2 w1, w2, w3; twtrip((float)k / (float)(4 * mh), w1, w2, w3);
      bfly4r(A, B, C, D, w1, w2, w3, 1.0f);
    } else {
      dft4(A, B, C, D, 1.0f);
    }
    s[SK(i0)] = A; s[SK(i0 + mh)] = B; s[SK(i0 + 2 * mh)] = C; s[SK(i0 + 3 * mh)] = D;
    __syncthreads();
  }
  // final radix-2 DIT combine + dB + max
  float lmax = -3.0e38f;
#pragma unroll
  for (int i = 0; i < 2; ++i) {
    const int p = tid + 512 * i;
    const float2 E = s[SK(p)];
    const float2 O = cmul(s[SK(p + 1024)], twid((float)p * (1.0f / 2048.0f)));
    const float2 y0 = make_float2(E.x + O.x, E.y + O.y);
    const float2 y1 = make_float2(E.x - O.x, E.y - O.y);
    const float d0 = 10.0f * __log10f(fmaxf(y0.x * y0.x + y0.y * y0.y, 1e-30f));
    const float d1 = 10.0f * __log10f(fmaxf(y1.x * y1.x + y1.y * y1.y, 1e-30f));
    Db[p] = d0; Db[p + 1024] = d1;
    lmax = fmaxf(lmax, fmaxf(d0, d1));
  }
  rmax[tid] = lmax;
  __syncthreads();
  for (int w = 256; w > 0; w >>= 1) {
    if (tid < w) rmax[tid] = fmaxf(rmax[tid], rmax[tid + w]);
    __syncthreads();
  }
  if (tid == 0) {
    const unsigned sb = __float_as_uint(rmax[0]);
    const unsigned key = (sb & 0x80000000u) ? ~sb : (sb | 0x80000000u);
    atomicMax((unsigned*)&red[blockIdx.z * slot4], key);
  }
}

// K8: transpose migdb (x-major) -> out (t-major) + normalize.
__global__ void __launch_bounds__(256) k_norm_tr(const float* __restrict__ migdb,
                                                 const float* __restrict__ red,
                                                 float* __restrict__ out,
                                                 size_t slot4, int b_base) {
  __shared__ float tile[32][33];
  const int tx = threadIdx.x & 31;
  const int ty = threadIdx.x >> 5;
  const int t0 = blockIdx.x * 32;
  const int x0 = blockIdx.y * 32;
  const float* Db = migdb + blockIdx.z * slot4;
  const unsigned kk = *(const unsigned*)&red[blockIdx.z * slot4];
  const float mx = (kk & 0x80000000u) ? __uint_as_float(kk & 0x7FFFFFFFu)
                                      : __uint_as_float(~kk);
  float* O = out + (size_t)(b_base + blockIdx.z) * NT * NX;
  for (int i = ty; i < 32; i += 8)
    tile[i][tx] = Db[(size_t)(x0 + i) * TDP + t0 + tx];
  __syncthreads();
  for (int i = ty; i < 32; i += 8) {
    float v = tile[tx][i] - mx;
    v = fmaxf(v, -70.0f);
    O[(size_t)(t0 + i) * NX + x0 + tx] = (v + 70.0f) * (1.0f / 70.0f);
  }
}

extern "C" void kernel_launch(void* const* d_in, const int* in_sizes, int n_in,
                              void* d_out, int out_size, void* d_ws, size_t ws_size,
                              hipStream_t stream) {
  const float* data = (const float*)d_in[0];
  float* out = (float*)d_out;
  char* ws = (char*)d_ws;

  // Per-slot layout: O1T (128 x NFP c64) | OT (512 x NFP c64) | TDT (257 x TDP c64) | red
  // Aliases: DT & migdb in TDT region; MIGT in O1T region.
  const size_t O1T_B = 0;
  const size_t OT_B  = (size_t)NX * NFP * sizeof(float2);
  const size_t TDT_B = OT_B + (size_t)NXF * NFP * sizeof(float2);
  const size_t RED_B = TDT_B + (size_t)257 * TDP * sizeof(float2);
  const size_t SLOT_B = ((RED_B + 1024 + 4095) / 4096) * 4096;
  const size_t slot4 = SLOT_B / 4, slot8 = SLOT_B / 8;
  const int slots = (ws_size >= (size_t)NBATCH * SLOT_B) ? NBATCH : 1;

  FKP P;
  {
    const double SA = std::sin(0.1), CA = std::cos(0.1);
    const double A1 = 1.0 + CA + SA * SA;
    const double beta = std::pow(1.0 + CA, 1.5) / A1;
    const double ds = 40000000.0 / 8192.0;
    P.ds = (float)ds;
    P.inv_ds = (float)(8192.0 / 40000000.0);
    P.inv_kx_den = (float)(1.0 / (0.0003 * 512.0));
    P.v_erm = (float)(1540.0 / std::sqrt(A1));
    P.kz_coef = (float)(2.0 / (beta * 1540.0));
    P.ph_rev = (float)(SA * 0.0003 * ds / 1540.0);
    P.dx_coef = (float)(-(SA / (2.0 - CA)) * 1540.0 / (2.0 * 40000000.0));
  }

  float2* o1t  = (float2*)(ws + O1T_B);
  float*  migt = (float*)(ws + O1T_B);     // alias
  float2* ot   = (float2*)(ws + OT_B);
  float2* tdt  = (float2*)(ws + TDT_B);
  float*  scr4 = (float*)(ws + TDT_B);     // alias: DT (pre-K4), migdb (post-K5)
  float*  red  = (float*)(ws + RED_B);

  for (int b0 = 0; b0 < NBATCH; b0 += slots) {
    k_tr     <<<dim3(64, 4, slots), 256, 0, stream>>>(data, scr4, red, slot4, b0);
    k_fft_t  <<<dim3(NX, 1, slots), 256, 0, stream>>>(scr4, o1t, slot4, slot8, P);
    k_fft_x  <<<dim3(513, 1, slots), 256, 0, stream>>>(o1t, ot, slot8, P);
    k_ifft_t <<<dim3(257, 1, slots), 512, 0, stream>>>(ot, tdt, slot8, P);
    k_c2r_x  <<<dim3(256, 1, slots), 256, 0, stream>>>(tdt, migt, slot8, slot4);
    k_hilbert<<<dim3(NX, 1, slots), 512, 0, stream>>>(migt, scr4, red, slot4);
    k_norm_tr<<<dim3(64, 4, slots), 256, 0, stream>>>(scr4, red, out, slot4, b0);
  }
}

// Round 11
// 156.738 us; speedup vs baseline: 1.0300x; 1.0300x over previous
//
#include <hip/hip_runtime.h>
#include <cmath>

#define NT 2048
#define NX 128
#define NXF 512
#define NF 4097
#define NFP 4104     // padded row length (complex) for f-axis rows
#define TDP 2056     // padded row length for t-axis rows
#define NBATCH 4
#define EPSF 1.1920929e-07f
#define SOUND_C 1540.0f

// LDS skew addressing: addr = e + 2*(e>>4). Bijective; <=2-way bank conflicts
// for every access pattern used here. 2-way is free on CDNA4.
__device__ __forceinline__ int SK(int e) { return e + 2 * (e >> 4); }

struct FKP {
  float ds, inv_ds, inv_kx_den, v_erm, kz_coef, ph_rev, dx_coef;
};

__device__ __forceinline__ float2 cmul(float2 a, float2 b) {
  return make_float2(a.x * b.x - a.y * b.y, a.x * b.y + a.y * b.x);
}
// e^{2*pi*i*u}, any u. v_cos/v_sin take REVOLUTIONS natively; fract reduces.
__device__ __forceinline__ float2 twid(float u) {
  const float f = u - floorf(u);
  return make_float2(__builtin_amdgcn_cosf(f), __builtin_amdgcn_sinf(f));
}
__device__ __forceinline__ float2 twidf(float u) { return twid(u); }
// Constant twiddle e^{sgn*2pi*i*k/16}, k in [0,4) compile-time -> literals.
__device__ __forceinline__ float2 twc16(int k, float sgn) {
  const float C[4]  = {1.0f, 0.923879532511f, 0.707106781187f, 0.382683432365f};
  const float Sn[4] = {0.0f, 0.382683432365f, 0.707106781187f, 0.923879532511f};
  return make_float2(C[k], sgn * Sn[k]);
}
// base-4 digit reversals
__device__ __forceinline__ int dr4_3(unsigned m) {
  unsigned r = __brev(m) >> 26;
  return (int)(((r & 0x15u) << 1) | ((r >> 1) & 0x15u));
}
__device__ __forceinline__ int dr4_4(unsigned m) {
  unsigned r = __brev(m) >> 24;
  return (int)(((r & 0x55u) << 1) | ((r >> 1) & 0x55u));
}
__device__ __forceinline__ int dr4_5(unsigned m) {
  unsigned r = __brev(m) >> 22;
  return (int)(((r & 0x155u) << 1) | ((r >> 1) & 0x155u));
}

// 4-pt DFT, no twiddle. sgn=-1 fwd, +1 inv.
__device__ __forceinline__ void dft4(float2& A, float2& B, float2& C, float2& D, float sgn) {
  float2 t0 = make_float2(A.x + C.x, A.y + C.y);
  float2 t1 = make_float2(A.x - C.x, A.y - C.y);
  float2 t2 = make_float2(B.x + D.x, B.y + D.y);
  float2 t3 = make_float2(B.x - D.x, B.y - D.y);
  float2 r  = make_float2(-sgn * t3.y, sgn * t3.x);
  A = make_float2(t0.x + t2.x, t0.y + t2.y);
  B = make_float2(t1.x + r.x, t1.y + r.y);
  C = make_float2(t0.x - t2.x, t0.y - t2.y);
  D = make_float2(t1.x - r.x, t1.y - r.y);
}
// DIT radix-4 butterfly with precomputed twiddles (pre-multiply then DFT4).
__device__ __forceinline__ void bfly4r(float2& A, float2& B, float2& C, float2& D,
                                       float2 w1, float2 w2, float2 w3, float sgn) {
  B = cmul(B, w1); C = cmul(C, w2); D = cmul(D, w3);
  dft4(A, B, C, D, sgn);
}
__device__ __forceinline__ void twtrip(float u, float2& w1, float2& w2, float2& w3) {
  w1 = twid(u); w2 = cmul(w1, w1); w3 = cmul(w2, w1);
}

// Merged radix-16 phase (two DIT radix-4 levels mh=S and mh=4S in registers).
// Level-2 twiddles derived from ONE base twiddle x constant rotations.
template<int S>
__device__ __forceinline__ void mstage(float2* __restrict__ s, int base, int kb, float sgn) {
  float2 w[16];
#pragma unroll
  for (int m = 0; m < 16; ++m) w[m] = s[SK(base + S * m)];
  {
    float2 a1, a2, a3; twtrip(sgn * (float)kb * (1.0f / (4 * S)), a1, a2, a3);
#pragma unroll
    for (int a = 0; a < 4; ++a)
      bfly4r(w[4 * a], w[4 * a + 1], w[4 * a + 2], w[4 * a + 3], a1, a2, a3, sgn);
  }
  {
    const float2 wb = twid(sgn * (float)kb * (1.0f / (16 * S)));
#pragma unroll
    for (int c = 0; c < 4; ++c) {
      float2 b1 = cmul(wb, twc16(c, sgn));
      float2 b2 = cmul(b1, b1);
      float2 b3 = cmul(b2, b1);
      bfly4r(w[c], w[4 + c], w[8 + c], w[12 + c], b1, b2, b3, sgn);
    }
  }
#pragma unroll
  for (int m = 0; m < 16; ++m) s[SK(base + S * m)] = w[m];
}

// K0: transpose input (nt,nx) -> DT (nx, TDP); also init per-slot max-key.
__global__ void __launch_bounds__(256) k_tr(const float* __restrict__ data,
                                            float* __restrict__ dt,
                                            float* __restrict__ red,
                                            size_t slot4, int b_base) {
  __shared__ float tile[32][33];
  if (threadIdx.x == 0 && blockIdx.x == 0 && blockIdx.y == 0)
    *(unsigned*)&red[blockIdx.z * slot4] = 0u;
  const int tx = threadIdx.x & 31;
  const int ty = threadIdx.x >> 5;
  const int t0 = blockIdx.x * 32;
  const int x0 = blockIdx.y * 32;
  const float* In = data + (size_t)(b_base + blockIdx.z) * NT * NX;
  float* Dt = dt + blockIdx.z * slot4;
  for (int i = ty; i < 32; i += 8)
    tile[i][tx] = In[(size_t)(t0 + i) * NX + x0 + tx];
  __syncthreads();
  for (int i = ty; i < 32; i += 8)
    Dt[(size_t)(x0 + i) * TDP + t0 + tx] = tile[tx][i];
}

// K1: per x, 8192-pt R2C FFT (4096 complex, 3 merged radix-16 phases) + phase.
// M1 inputs load DIRECTLY from the 8KB L1-resident DT row at digit-reversed
// offsets (no LDS staging, no staging barrier) — latency-bound regime, fewer
// barriers > fewer scattered-but-cached loads.
__global__ void __launch_bounds__(256) k_fft_t(const float* __restrict__ dt,
                                               float2* __restrict__ o1t,
                                               size_t slot4, size_t slot8, FKP P) {
  __shared__ float2 s[4608];
  const int x = blockIdx.x, tid = threadIdx.x;
  const float2* row2 = (const float2*)(dt + blockIdx.z * slot4 + (size_t)x * TDP);
  float2* O1 = o1t + blockIdx.z * slot8 + (size_t)x * NFP;
  // M1: merged stages (1,4); input zero-structure -> broadcast + level-2 bfly.
  {
    const int m0 = dr4_4((unsigned)tid);
    const float2 v0 = row2[m0];
    const float2 v1 = row2[m0 + 256];
    const float2 v2 = row2[m0 + 512];
    const float2 v3 = row2[m0 + 768];
    const int base = tid << 4;
#pragma unroll
    for (int k = 0; k < 4; ++k) {
      float2 A = v0, B = v1, C = v2, D = v3;
      if (k == 0) {
        dft4(A, B, C, D, -1.0f);
      } else {
        float2 w1 = twc16(k, -1.0f);
        float2 w2 = cmul(w1, w1);
        float2 w3 = cmul(w2, w1);
        bfly4r(A, B, C, D, w1, w2, w3, -1.0f);
      }
      s[SK(base + k)] = A; s[SK(base + 4 + k)] = B;
      s[SK(base + 8 + k)] = C; s[SK(base + 12 + k)] = D;
    }
  }
  __syncthreads();
  mstage<16>(s, ((tid >> 4) << 8) | (tid & 15), tid & 15, -1.0f);
  __syncthreads();
  mstage<256>(s, tid, tid, -1.0f);
  __syncthreads();
  // R2C unpack + t_delay phase
  for (int k = tid; k < NF; k += 256) {
    const int ka = k & 4095, kb = (4096 - k) & 4095;
    const float2 Ck = s[SK(ka)];
    const float2 Cm = s[SK(kb)];
    float2 E = make_float2(0.5f * (Ck.x + Cm.x), 0.5f * (Ck.y - Cm.y));
    float2 T = make_float2(0.5f * (Ck.x - Cm.x), 0.5f * (Ck.y + Cm.y));
    float2 WT = cmul(twid((float)k * (-1.0f / 8192.0f)), T);
    float2 X = make_float2(E.x + WT.y, E.y - WT.x);   // E - i*(W*T)
    float2 ph = twidf(P.ph_rev * (float)(x * k));
    O1[k] = cmul(X, ph);
  }
}

// K2: per 8 f-rows, 512-pt FFT along x (2*4^4), evanescent mask, transposed
// write OT[j][i]. Staged structure, 512 threads -> 4 blocks/CU = 32 waves
// (latency-bound regime: wave count beats LDS-traffic savings — r10 lesson).
#define R2P 580
__global__ void __launch_bounds__(512) k_fft_x(const float2* __restrict__ o1t,
                                               float2* __restrict__ ot,
                                               size_t slot8, FKP P) {
  __shared__ float2 s[8 * R2P];
  const int i0 = blockIdx.x * 8;
  const int tid = threadIdx.x;
  const float2* O1 = o1t + blockIdx.z * slot8;
  float2* OT = ot + blockIdx.z * slot8;
  for (int idx = tid; idx < 128 * 8; idx += 512) {
    const int ii = idx & 7, x = idx >> 3;
    const int i = i0 + ii;
    float2 v = (i < NF) ? O1[(size_t)x * NFP + i] : make_float2(0.f, 0.f);
    float2* r = s + ii * R2P;
    const int p = ((x & 1) << 8) + 4 * dr4_3((unsigned)(x >> 1));
    r[SK(p)] = v; r[SK(p + 1)] = v; r[SK(p + 2)] = v; r[SK(p + 3)] = v;
  }
  __syncthreads();
  for (int mh = 4; mh <= 64; mh *= 4) {
    const float inv = -1.0f / (float)(4 * mh);
    for (int t = tid; t < 8 * 128; t += 512) {
      const int row = t >> 7, tt = t & 127;
      const int half = tt >> 6, q = tt & 63;
      const int k = q & (mh - 1);
      const int i0b = ((q & ~(mh - 1)) << 2) + k + (half << 8);
      float2* r = s + row * R2P;
      float2 A = r[SK(i0b)], B = r[SK(i0b + mh)], C = r[SK(i0b + 2 * mh)], D = r[SK(i0b + 3 * mh)];
      float2 w1, w2, w3; twtrip((float)k * inv, w1, w2, w3);
      bfly4r(A, B, C, D, w1, w2, w3, -1.0f);
      r[SK(i0b)] = A; r[SK(i0b + mh)] = B; r[SK(i0b + 2 * mh)] = C; r[SK(i0b + 3 * mh)] = D;
    }
    __syncthreads();
  }
  for (int t = tid; t < 8 * 256; t += 512) {
    const int row = t >> 8, k = t & 255;
    float2* r = s + row * R2P;
    float2 E = r[SK(k)], O = r[SK(256 + k)];
    float2 WO = cmul(twid((float)k * (-1.0f / 512.0f)), O);
    r[SK(k)]       = make_float2(E.x + WO.x, E.y + WO.y);
    r[SK(256 + k)] = make_float2(E.x - WO.x, E.y - WO.y);
  }
  __syncthreads();
  for (int idx = tid; idx < 512 * 8; idx += 512) {
    const int j = idx >> 3, ii = idx & 7;
    const int i = i0 + ii;
    if (i >= NF) continue;
    const float f = P.ds * (float)i;
    const int kn = (j <= 256) ? j : j - 512;
    const float kx = fabsf((float)kn * P.inv_kx_den);
    float2 v = (f / (kx + EPSF) < SOUND_C) ? make_float2(0.f, 0.f)
                                           : s[ii * R2P + SK(j)];
    OT[(size_t)j * NFP + i] = v;
  }
}

// K4: per kx-column j in [0,256]: Stolt gather at digit-reversed positions
// fused with merged stages (1,4); then 2 merged radix-16 phases and the cross
// radix-2; dx-phase; writes TDT[j][t], t<NT. Unscaled.
__global__ void __launch_bounds__(512) k_ifft_t(const float2* __restrict__ ot,
                                                float2* __restrict__ tdt,
                                                size_t slot8, FKP P) {
  __shared__ float2 s[9216];
  const int j = blockIdx.x;                  // 0..256
  const int jm = (NXF - j) & (NXF - 1);
  const int t = threadIdx.x;
  const float2* OT = ot + blockIdx.z * slot8;
  float2* T = tdt + blockIdx.z * slot8 + (size_t)j * TDP;
  const float kxj = (float)j * P.inv_kx_den;
  const float kx2 = kxj * kxj;
  const float2* rowj = OT + (size_t)j * NFP;
  const float2* rowm = OT + (size_t)jm * NFP;
  // M1: thread owns digit-rev positions 16t..16t+15. Position 16t+m holds
  // spectrum sample n = 2*(1024*(m&3) + 256*(m>>2) + dr4_4(t&255)) + (t>>8).
  {
    const int tau = t & 255, half = t >> 8;
    const int m0 = dr4_4((unsigned)tau);
    float2 w[16];
#pragma unroll
    for (int m = 0; m < 16; ++m) {
      const int ci = (m & 3) * 1024 + (m >> 2) * 256 + m0;
      const int n = 2 * ci + half;
      const bool mir = (n > 4096);
      const int r = mir ? (8192 - n) : n;
      const float2* rw = mir ? rowm : rowj;
      float2 v = make_float2(0.f, 0.f);
      if (r > 0) {
        const float f = P.ds * (float)r;
        const float kz = f * P.kz_coef;
        const float fkz = P.v_erm * sqrtf(kx2 + kz * kz);
        const float iq = fkz * P.inv_ds;
        if (iq < 4095.0f) {
          const float flf = floorf(iq);
          const int fl = (int)flf;
          const float lw = iq - flf;
          const float2 v0 = rw[fl], v1 = rw[fl + 1];
          const float sc = f / (fkz + EPSF);
          v.x = (v0.x + (v1.x - v0.x) * lw) * sc;
          v.y = (v0.y + (v1.y - v0.y) * lw) * (mir ? -sc : sc);
        }
      }
      w[m] = v;
    }
#pragma unroll
    for (int a = 0; a < 4; ++a) dft4(w[4 * a], w[4 * a + 1], w[4 * a + 2], w[4 * a + 3], 1.0f);
    dft4(w[0], w[4], w[8], w[12], 1.0f);
#pragma unroll
    for (int k = 1; k < 4; ++k) {
      float2 w1 = twc16(k, 1.0f);
      float2 w2 = cmul(w1, w1);
      float2 w3 = cmul(w2, w1);
      bfly4r(w[k], w[4 + k], w[8 + k], w[12 + k], w1, w2, w3, 1.0f);
    }
    const int base = t << 4;
#pragma unroll
    for (int m = 0; m < 16; ++m) s[SK(base + m)] = w[m];
  }
  __syncthreads();
  mstage<16>(s, ((t >> 4) << 8) | (t & 15), t & 15, 1.0f);
  __syncthreads();
  mstage<256>(s, ((t >> 8) << 12) | (t & 255), t & 255, 1.0f);
  __syncthreads();
  // cross radix-2 (only outputs t<2048 needed) + dx-phase
  const float dxr = -kxj * P.dx_coef;
#pragma unroll
  for (int i = 0; i < 4; ++i) {
    const int k = t + 512 * i;
    const float2 E = s[SK(k)];
    const float2 O = s[SK(4096 + k)];
    const float2 WO = cmul(twid((float)k * (1.0f / 8192.0f)), O);
    const float2 y = make_float2(E.x + WO.x, E.y + WO.y);
    T[k] = cmul(y, twidf(dxr * (float)k));
  }
}

// K5: per 8 t-rows: Hermitian C2R 512-pt inverse x-FFT via 256-pt complex
// IFFT; writes real MIGT[x][t]. Unscaled. DC/Nyquist Im projected out.
#define SXA 260
#define SXC 292
__global__ void __launch_bounds__(256) k_c2r_x(const float2* __restrict__ tdt,
                                               float* __restrict__ migt,
                                               size_t slot8, size_t slot4) {
  __shared__ float2 sx[8 * SXA];
  __shared__ float2 sc[8 * SXC];
  const int t0 = blockIdx.x * 8;
  const int tid = threadIdx.x;
  const float2* T = tdt + blockIdx.z * slot8;
  float* M = migt + blockIdx.z * slot4;
  for (int idx = tid; idx < 257 * 8; idx += 256) {
    const int tt = idx & 7, jj = idx >> 3;
    float2 v = T[(size_t)jj * TDP + t0 + tt];
    if (jj == 0 || jj == 256) v.y = 0.0f;
    sx[tt * SXA + jj] = v;
  }
  __syncthreads();
  for (int idx = tid; idx < 129 * 8; idx += 256) {
    const int row = idx & 7, k = idx >> 3;
    const float2* X = sx + row * SXA;
    float2* Cb = sc + row * SXC;
    const float2 Xk = X[k];
    const float2 Xm = X[256 - k];
    float2 Ef = make_float2(0.5f * (Xk.x + Xm.x), 0.5f * (Xk.y - Xm.y));
    float2 Tm = make_float2(0.5f * (Xk.x - Xm.x), 0.5f * (Xk.y + Xm.y));
    float2 Of = cmul(twid((float)k * (1.0f / 512.0f)), Tm);
    Cb[SK(dr4_4((unsigned)k))] = make_float2(Ef.x - Of.y, Ef.y + Of.x);
    if (k > 0 && k < 128)
      Cb[SK(dr4_4((unsigned)(256 - k)))] = make_float2(Ef.x + Of.y, Of.x - Ef.y);
  }
  __syncthreads();
  for (int mh = 1; mh <= 64; mh *= 4) {
    const float inv = 1.0f / (float)(4 * mh);
    for (int t = tid; t < 8 * 64; t += 256) {
      const int row = t >> 6, q = t & 63;
      const int k = q & (mh - 1);
      const int i0 = ((q & ~(mh - 1)) << 2) + k;
      float2* r = sc + row * SXC;
      float2 A = r[SK(i0)], B = r[SK(i0 + mh)], C = r[SK(i0 + 2 * mh)], D = r[SK(i0 + 3 * mh)];
      if (mh > 1) {
        float2 w1, w2, w3; twtrip((float)k * inv, w1, w2, w3);
        bfly4r(A, B, C, D, w1, w2, w3, 1.0f);
      } else {
        dft4(A, B, C, D, 1.0f);
      }
      r[SK(i0)] = A; r[SK(i0 + mh)] = B; r[SK(i0 + 2 * mh)] = C; r[SK(i0 + 3 * mh)] = D;
    }
    __syncthreads();
  }
  for (int idx = tid; idx < 128 * 8; idx += 256) {
    const int x = idx >> 3, tt = idx & 7;
    const float2 c = sc[tt * SXC + SK(x >> 1)];
    M[(size_t)x * TDP + t0 + tt] = (x & 1) ? c.y : c.x;
  }
}

// K6: per x-column Hilbert (2048 = 2*4^5 mixed DIF -> mask(digit-rev) -> DIT)
// + dB via 10*log10(mag^2); block max -> monotone-uint atomicMax.
__global__ void __launch_bounds__(512) k_hilbert(const float* __restrict__ migt,
                                                 float* __restrict__ migdb,
                                                 float* __restrict__ red,
                                                 size_t slot4) {
  __shared__ float2 s[2304];
  __shared__ float rmax[512];
  const int x = blockIdx.x, tid = threadIdx.x;
  const float* Mr = migt + blockIdx.z * slot4 + (size_t)x * TDP;
  float* Db = migdb + blockIdx.z * slot4 + (size_t)x * TDP;
#pragma unroll
  for (int i = 0; i < 4; ++i) {
    const int p = tid + 512 * i;
    s[SK(p)] = make_float2(Mr[p], 0.0f);
  }
  __syncthreads();
  // forward: radix-2 DIF (stride 1024), post-twiddle W^-p
#pragma unroll
  for (int i = 0; i < 2; ++i) {
    const int p = tid + 512 * i;
    const float2 a = s[SK(p)], b = s[SK(p + 1024)];
    s[SK(p)] = make_float2(a.x + b.x, a.y + b.y);
    s[SK(p + 1024)] = cmul(make_float2(a.x - b.x, a.y - b.y),
                           twid(-(float)p * (1.0f / 2048.0f)));
  }
  __syncthreads();
  // per-half radix-4 DIF stages
  for (int mh = 256; mh >= 1; mh >>= 2) {
    const int half = tid >> 8, q = tid & 255;
    const int k = q & (mh - 1);
    const int i0 = (half << 10) + ((q & ~(mh - 1)) << 2) + k;
    float2 A = s[SK(i0)], B = s[SK(i0 + mh)], C = s[SK(i0 + 2 * mh)], D = s[SK(i0 + 3 * mh)];
    dft4(A, B, C, D, -1.0f);
    if (mh > 1) {
      float2 w1, w2, w3; twtrip(-(float)k / (float)(4 * mh), w1, w2, w3);
      B = cmul(B, w1); C = cmul(C, w2); D = cmul(D, w3);
    }
    s[SK(i0)] = A; s[SK(i0 + mh)] = B; s[SK(i0 + 2 * mh)] = C; s[SK(i0 + 3 * mh)] = D;
    __syncthreads();
  }
  // h-mask; position p holds freq k = 2*dr4_5(p&1023) + (p>>10)
#pragma unroll
  for (int i = 0; i < 4; ++i) {
    const int p = tid + 512 * i;
    const int kk = 2 * dr4_5((unsigned)(p & 1023)) + (p >> 10);
    const float hv = (kk == 0 || kk == 1024) ? 1.0f : ((kk < 1024) ? 2.0f : 0.0f);
    float2 v = s[SK(p)];
    s[SK(p)] = make_float2(v.x * hv, v.y * hv);
  }
  __syncthreads();
  // inverse: per-half radix-4 DIT stages
  for (int mh = 1; mh <= 256; mh <<= 2) {
    const int half = tid >> 8, q = tid & 255;
    const int k = q & (mh - 1);
    const int i0 = (half << 10) + ((q & ~(mh - 1)) << 2) + k;
    float2 A = s[SK(i0)], B = s[SK(i0 + mh)], C = s[SK(i0 + 2 * mh)], D = s[SK(i0 + 3 * mh)];
    if (mh > 1) {
      float2 w1, w2, w3; twtrip((float)k / (float)(4 * mh), w1, w2, w3);
      bfly4r(A, B, C, D, w1, w2, w3, 1.0f);
    } else {
      dft4(A, B, C, D, 1.0f);
    }
    s[SK(i0)] = A; s[SK(i0 + mh)] = B; s[SK(i0 + 2 * mh)] = C; s[SK(i0 + 3 * mh)] = D;
    __syncthreads();
  }
  // final radix-2 DIT combine + dB + max
  float lmax = -3.0e38f;
#pragma unroll
  for (int i = 0; i < 2; ++i) {
    const int p = tid + 512 * i;
    const float2 E = s[SK(p)];
    const float2 O = cmul(s[SK(p + 1024)], twid((float)p * (1.0f / 2048.0f)));
    const float2 y0 = make_float2(E.x + O.x, E.y + O.y);
    const float2 y1 = make_float2(E.x - O.x, E.y - O.y);
    const float d0 = 10.0f * __log10f(fmaxf(y0.x * y0.x + y0.y * y0.y, 1e-30f));
    const float d1 = 10.0f * __log10f(fmaxf(y1.x * y1.x + y1.y * y1.y, 1e-30f));
    Db[p] = d0; Db[p + 1024] = d1;
    lmax = fmaxf(lmax, fmaxf(d0, d1));
  }
  rmax[tid] = lmax;
  __syncthreads();
  for (int w = 256; w > 0; w >>= 1) {
    if (tid < w) rmax[tid] = fmaxf(rmax[tid], rmax[tid + w]);
    __syncthreads();
  }
  if (tid == 0) {
    const unsigned sb = __float_as_uint(rmax[0]);
    const unsigned key = (sb & 0x80000000u) ? ~sb : (sb | 0x80000000u);
    atomicMax((unsigned*)&red[blockIdx.z * slot4], key);
  }
}

// K8: transpose migdb (x-major) -> out (t-major) + normalize.
__global__ void __launch_bounds__(256) k_norm_tr(const float* __restrict__ migdb,
                                                 const float* __restrict__ red,
                                                 float* __restrict__ out,
                                                 size_t slot4, int b_base) {
  __shared__ float tile[32][33];
  const int tx = threadIdx.x & 31;
  const int ty = threadIdx.x >> 5;
  const int t0 = blockIdx.x * 32;
  const int x0 = blockIdx.y * 32;
  const float* Db = migdb + blockIdx.z * slot4;
  const unsigned kk = *(const unsigned*)&red[blockIdx.z * slot4];
  const float mx = (kk & 0x80000000u) ? __uint_as_float(kk & 0x7FFFFFFFu)
                                      : __uint_as_float(~kk);
  float* O = out + (size_t)(b_base + blockIdx.z) * NT * NX;
  for (int i = ty; i < 32; i += 8)
    tile[i][tx] = Db[(size_t)(x0 + i) * TDP + t0 + tx];
  __syncthreads();
  for (int i = ty; i < 32; i += 8) {
    float v = tile[tx][i] - mx;
    v = fmaxf(v, -70.0f);
    O[(size_t)(t0 + i) * NX + x0 + tx] = (v + 70.0f) * (1.0f / 70.0f);
  }
}

extern "C" void kernel_launch(void* const* d_in, const int* in_sizes, int n_in,
                              void* d_out, int out_size, void* d_ws, size_t ws_size,
                              hipStream_t stream) {
  const float* data = (const float*)d_in[0];
  float* out = (float*)d_out;
  char* ws = (char*)d_ws;

  // Per-slot layout: O1T (128 x NFP c64) | OT (512 x NFP c64) | TDT (257 x TDP c64) | red
  // Aliases: DT & migdb in TDT region; MIGT in O1T region.
  const size_t O1T_B = 0;
  const size_t OT_B  = (size_t)NX * NFP * sizeof(float2);
  const size_t TDT_B = OT_B + (size_t)NXF * NFP * sizeof(float2);
  const size_t RED_B = TDT_B + (size_t)257 * TDP * sizeof(float2);
  const size_t SLOT_B = ((RED_B + 1024 + 4095) / 4096) * 4096;
  const size_t slot4 = SLOT_B / 4, slot8 = SLOT_B / 8;
  const int slots = (ws_size >= (size_t)NBATCH * SLOT_B) ? NBATCH : 1;

  FKP P;
  {
    const double SA = std::sin(0.1), CA = std::cos(0.1);
    const double A1 = 1.0 + CA + SA * SA;
    const double beta = std::pow(1.0 + CA, 1.5) / A1;
    const double ds = 40000000.0 / 8192.0;
    P.ds = (float)ds;
    P.inv_ds = (float)(8192.0 / 40000000.0);
    P.inv_kx_den = (float)(1.0 / (0.0003 * 512.0));
    P.v_erm = (float)(1540.0 / std::sqrt(A1));
    P.kz_coef = (float)(2.0 / (beta * 1540.0));
    P.ph_rev = (float)(SA * 0.0003 * ds / 1540.0);
    P.dx_coef = (float)(-(SA / (2.0 - CA)) * 1540.0 / (2.0 * 40000000.0));
  }

  float2* o1t  = (float2*)(ws + O1T_B);
  float*  migt = (float*)(ws + O1T_B);     // alias
  float2* ot   = (float2*)(ws + OT_B);
  float2* tdt  = (float2*)(ws + TDT_B);
  float*  scr4 = (float*)(ws + TDT_B);     // alias: DT (pre-K4), migdb (post-K5)
  float*  red  = (float*)(ws + RED_B);

  for (int b0 = 0; b0 < NBATCH; b0 += slots) {
    k_tr     <<<dim3(64, 4, slots), 256, 0, stream>>>(data, scr4, red, slot4, b0);
    k_fft_t  <<<dim3(NX, 1, slots), 256, 0, stream>>>(scr4, o1t, slot4, slot8, P);
    k_fft_x  <<<dim3(513, 1, slots), 512, 0, stream>>>(o1t, ot, slot8, P);
    k_ifft_t <<<dim3(257, 1, slots), 512, 0, stream>>>(ot, tdt, slot8, P);
    k_c2r_x  <<<dim3(256, 1, slots), 256, 0, stream>>>(tdt, migt, slot8, slot4);
    k_hilbert<<<dim3(NX, 1, slots), 512, 0, stream>>>(migt, scr4, red, slot4);
    k_norm_tr<<<dim3(64, 4, slots), 256, 0, stream>>>(scr4, red, out, slot4, b0);
  }
}